// Round 3
// baseline (1009.830 us; speedup 1.0000x reference)
//
#include <hip/hip_runtime.h>

typedef unsigned short u16;
typedef unsigned int   u32;
typedef short bf16x8 __attribute__((ext_vector_type(8)));
typedef float f32x4  __attribute__((ext_vector_type(4)));

#define KT 5824   // 5760 (x_q) + 32 (t) + 32 (zero pad)

__device__ __forceinline__ u16 bf16_rtne(float f) {
  u32 u = __builtin_bit_cast(u32, f);
  u += 0x7fffu + ((u >> 16) & 1u);
  return (u16)(u >> 16);
}

__device__ __forceinline__ u32 pack2(float a, float b) {
  return (u32)bf16_rtne(a) | ((u32)bf16_rtne(b) << 16);
}

__device__ __forceinline__ float fq1(float v, float inv, float s) {
  return fminf(fmaxf(rintf(v * inv), -8.f), 7.f) * s;
}

// ---------------------------------------------------------------------------
// Weight prep: Bt[n][k] = (k<5760 ? qweight[k][n]*wscales[k/64][n]
//                          : k<5792 ? proj_up[k-5760][n] : 0), bf16, k-contig.
// ---------------------------------------------------------------------------
__global__ __launch_bounds__(256) void wprep(const float* __restrict__ qw,
                                             const float* __restrict__ wsc,
                                             const float* __restrict__ pu,
                                             u16* __restrict__ Bt) {
  __shared__ u16 tile[64 * 66];
  const int tid = threadIdx.x;
  const int k0 = blockIdx.x * 64, n0 = blockIdx.y * 64;
  {
    const int n = tid & 63, kk = tid >> 6;
    const float wv = (k0 < 5760) ? wsc[(size_t)(k0 >> 6) * 640 + n0 + n] : 0.f;
    for (int p = 0; p < 16; ++p) {
      const int k = p * 4 + kk;
      const int gk = k0 + k;
      float v;
      if (gk < 5760)      v = qw[(size_t)gk * 640 + n0 + n] * wv;
      else if (gk < 5792) v = pu[(size_t)(gk - 5760) * 640 + n0 + n];
      else                v = 0.f;
      tile[k * 66 + n] = bf16_rtne(v);
    }
  }
  __syncthreads();
  {
    const int k = tid & 63, nn = tid >> 6;
    for (int p = 0; p < 16; ++p) {
      const int n2 = p * 4 + nn;
      Bt[(size_t)(n0 + n2) * KT + k0 + k] = tile[k * 66 + n2];
    }
  }
}

// ---------------------------------------------------------------------------
// pd prep: pack proj_down (5760x32 f32) into per-group MFMA B-operand frags.
// ---------------------------------------------------------------------------
__global__ __launch_bounds__(256) void pdprep(const float* __restrict__ pd,
                                              u16* __restrict__ pdp) {
  const int g = blockIdx.x;
  const int f = threadIdx.x >> 6, l = threadIdx.x & 63;
  const int kc = f >> 1, nt = f & 1;
  const int k = g * 64 + kc * 32 + ((l >> 4) * 8);
  const int r = nt * 16 + (l & 15);
  u32 w[4];
  for (int jj = 0; jj < 4; ++jj)
    w[jj] = pack2(pd[(size_t)(k + 2 * jj) * 32 + r], pd[(size_t)(k + 2 * jj + 1) * 32 + r]);
  *(uint4*)(pdp + ((size_t)(g * 4 + f) * 64 + l) * 8) = make_uint4(w[0], w[1], w[2], w[3]);
}

// ---------------------------------------------------------------------------
// FUSED quant + rank-32 + GEMM. 256 blocks (1/CU) x 512 threads (8 waves).
// Block owns 64 m-rows x ALL 640 n-cols -> x read exactly ONCE from HBM,
// A-matrix workspace round-trip eliminated entirely.
//   Per K-tile (64 k): phase1: x (reg-prefetched 1 tile ahead) -> group-max
//   quant -> Aq LDS (chunk-XOR swizzle) + raw bf16 -> xr LDS. Raw
//   lgkmcnt(0)+s_barrier (NOT __syncthreads: must not drain the x-prefetch
//   vmcnt). phase2: 40 main MFMA (B-frags direct from L2-resident Bt, no LDS
//   staging) + 2 t-MFMA (x_raw @ pd, per-wave f32x4 frag).
//   kt==90: phase1 drains tacc as bf16 into Aq (k=5760..5791 = t, rest 0),
//   phase2 multiplies vs Bt rows 5760.. (= pu, zeros pad) -> same numerics
//   as the old prep+gemm pipeline (identical quant values, same K order).
//   Wave grid: wm=w&1 (32 m-rows), wn=w>>1 (160 n-cols): acc[2][10].
//   t-frags: mtt=w&3 (16 rows), rt=w>>2 (rank half) -> 8 waves cover 64x32.
// ---------------------------------------------------------------------------
__global__ __launch_bounds__(512, 2) void fgemm(const float* __restrict__ x,
                                                const u16* __restrict__ Bt,
                                                const u16* __restrict__ pdp,
                                                const float* __restrict__ bias,
                                                float* __restrict__ out) {
  __shared__ u16 Aq[64 * 64];   // quantized (or t) tile, chunk-swizzled
  __shared__ u16 xr[64 * 64];   // raw bf16 tile, chunk-swizzled
  const int tid = threadIdx.x;
  const int lane = tid & 63;
  const int w = tid >> 6;               // 0..7
  const int wm = w & 1, wn = w >> 1;    // main-GEMM wave grid
  const int m0 = blockIdx.x * 64;
  const int r8 = lane >> 3, c8 = lane & 7;
  const int srow = w * 8 + r8;          // staging row 0..63
  const int frow = lane & 15, fq = lane >> 4;
  const int mtt = w & 3, rt = w >> 2;   // t-fragment assignment

  f32x4 acc[2][10] = {};
  f32x4 tacc = {};

  const float* px = x + (size_t)(m0 + srow) * 5760 + c8 * 8;
  float4 v0 = *(const float4*)px;       // prefetch K-tile 0
  float4 v1 = *(const float4*)(px + 4);

#pragma unroll 1
  for (int kt = 0; kt < 91; ++kt) {
    // -------- phase 1: produce Aq (+xr) --------
    if (kt < 90) {
      float4 c0 = v0, c1 = v1;
      if (kt < 89) {                    // prefetch next x tile (consumed next iter)
        const float* pn = px + (size_t)(kt + 1) * 64;
        v0 = *(const float4*)pn;
        v1 = *(const float4*)(pn + 4);
      }
      float mx = fmaxf(fmaxf(fmaxf(fabsf(c0.x), fabsf(c0.y)), fmaxf(fabsf(c0.z), fabsf(c0.w))),
                       fmaxf(fmaxf(fabsf(c1.x), fabsf(c1.y)), fmaxf(fabsf(c1.z), fabsf(c1.w))));
      mx = fmaxf(mx, __shfl_xor(mx, 1, 64));
      mx = fmaxf(mx, __shfl_xor(mx, 2, 64));
      mx = fmaxf(mx, __shfl_xor(mx, 4, 64));
      const float s = fmaxf(mx / 7.0f, 1e-6f);
      const float inv = 1.0f / s;
      uint4 qv = make_uint4(pack2(fq1(c0.x, inv, s), fq1(c0.y, inv, s)),
                            pack2(fq1(c0.z, inv, s), fq1(c0.w, inv, s)),
                            pack2(fq1(c1.x, inv, s), fq1(c1.y, inv, s)),
                            pack2(fq1(c1.z, inv, s), fq1(c1.w, inv, s)));
      *(uint4*)&Aq[srow * 64 + ((c8 ^ r8) * 8)] = qv;
      uint4 rv = make_uint4(pack2(c0.x, c0.y), pack2(c0.z, c0.w),
                            pack2(c1.x, c1.y), pack2(c1.z, c1.w));
      *(uint4*)&xr[srow * 64 + ((c8 ^ r8) * 8)] = rv;
    } else {
      // t-drain: wave's tacc frag -> Aq rows mtt*16+fq*4+r0, col rt*16+frow
      const int col = rt * 16 + frow;
      const int ch = col >> 3, co = col & 7;
      const int zc = 4 + (frow & 3);    // zero chunks 4..7 (redundant-safe)
#pragma unroll
      for (int r0 = 0; r0 < 4; ++r0) {
        const int rr = mtt * 16 + fq * 4 + r0;
        Aq[rr * 64 + ((ch ^ (rr & 7)) * 8) + co] = bf16_rtne(tacc[r0]);
        *(uint4*)&Aq[rr * 64 + ((zc ^ (rr & 7)) * 8)] = make_uint4(0, 0, 0, 0);
      }
    }
    asm volatile("s_waitcnt lgkmcnt(0)" ::: "memory");
    __builtin_amdgcn_s_barrier();

    // -------- phase 2: MFMA --------
    const size_t kOff = (size_t)kt * 64;
#pragma unroll
    for (int kc = 0; kc < 2; ++kc) {
      const int ch = kc * 4 + fq;
      const int sw = (ch ^ (frow & 7)) * 8;
      bf16x8 bfr[10];
#pragma unroll
      for (int nt = 0; nt < 10; ++nt)
        bfr[nt] = *(const bf16x8*)(Bt + (size_t)(wn * 160 + nt * 16 + frow) * KT + kOff + ch * 8);
      bf16x8 af0 = *(const bf16x8*)&Aq[(wm * 32 + frow) * 64 + sw];
      bf16x8 af1 = *(const bf16x8*)&Aq[(wm * 32 + 16 + frow) * 64 + sw];
#pragma unroll
      for (int nt = 0; nt < 10; ++nt) {
        acc[0][nt] = __builtin_amdgcn_mfma_f32_16x16x32_bf16(bfr[nt], af0, acc[0][nt], 0, 0, 0);
        acc[1][nt] = __builtin_amdgcn_mfma_f32_16x16x32_bf16(bfr[nt], af1, acc[1][nt], 0, 0, 0);
      }
      if (kt < 90) {
        bf16x8 xf = *(const bf16x8*)&xr[(mtt * 16 + frow) * 64 + sw];
        bf16x8 pf = *(const bf16x8*)(pdp + ((size_t)(kt * 4 + kc * 2 + rt) * 64 + lane) * 8);
        tacc = __builtin_amdgcn_mfma_f32_16x16x32_bf16(xf, pf, tacc, 0, 0, 0);
      }
    }
    asm volatile("s_waitcnt lgkmcnt(0)" ::: "memory");
    __builtin_amdgcn_s_barrier();
  }

  // Epilogue: c = wn*160+nt*16+fq*4+r; m = m0+wm*32+mt*16+frow (transposed).
  const int batch = m0 >> 12;
  float* outb = out + (size_t)batch * (640 * 4096) + (m0 & 4095) + wm * 32 + frow;
  const int cb = wn * 160 + fq * 4;
#pragma unroll
  for (int nt = 0; nt < 10; ++nt) {
#pragma unroll
    for (int r = 0; r < 4; ++r) {
      const int c = cb + nt * 16 + r;
      const float bv = bias[c];
      float* op = outb + (size_t)c * 4096;
      op[0]  = acc[0][nt][r] + bv;
      op[16] = acc[1][nt][r] + bv;
    }
  }
}

// ---------------------------------------------------------------------------
// ws layout: Bt  @ 0       : 640*5824*2 = 7,454,720 B
//            pdp @ 7454720 : 90*4*64*16 =   368,640 B   (total 7.8 MB)
// (A workspace eliminated by fusion.)
// ---------------------------------------------------------------------------
extern "C" void kernel_launch(void* const* d_in, const int* in_sizes, int n_in,
                              void* d_out, int out_size, void* d_ws, size_t ws_size,
                              hipStream_t stream) {
  const float* x    = (const float*)d_in[0];
  const float* qw   = (const float*)d_in[1];
  const float* wsc  = (const float*)d_in[2];
  const float* pd   = (const float*)d_in[3];
  const float* pu   = (const float*)d_in[4];
  const float* bias = (const float*)d_in[5];
  float* out = (float*)d_out;
  char* wsb = (char*)d_ws;
  u16* Bt  = (u16*)wsb;
  u16* pdp = (u16*)(wsb + 7454720);

  wprep<<<dim3(91, 10), dim3(256), 0, stream>>>(qw, wsc, pu, Bt);
  pdprep<<<dim3(90), dim3(256), 0, stream>>>(pd, pdp);
  fgemm<<<dim3(256), dim3(512), 0, stream>>>(x, Bt, pdp, bias, out);
}